// Round 18
// baseline (399.324 us; speedup 1.0000x reference)
//
#include <hip/hip_runtime.h>

// Problem constants (from reference)
#define IN_CH   256
#define OUT_CH  128
#define SCALE   1.8f
#define GT_M    32      // GEMM rows per block (2 row-tiles per wave; 17KB LDS -> 8 blocks/CU)
#define BKT_SH  8       // 256 nodes per bucket
#define BKT_CAP 9216    // fixed bucket window capacity (mean 8192 + 11 sigma)

using bf16x8 = __attribute__((ext_vector_type(8))) short;   // 8 bf16 = 4 VGPR
using f32x4  = __attribute__((ext_vector_type(4))) float;

// bf16 helpers (bit-level, round-to-nearest-even on pack)
__device__ __forceinline__ float blo(unsigned int w) { return __uint_as_float(w << 16); }
__device__ __forceinline__ float bhi(unsigned int w) { return __uint_as_float(w & 0xffff0000u); }
__device__ __forceinline__ unsigned short f2b(float f) {
    unsigned int u = __float_as_uint(f);
    u += 0x7fffu + ((u >> 16) & 1u);
    return (unsigned short)(u >> 16);
}
// split float -> hi bf16 + lo bf16 (residual)
__device__ __forceinline__ void split2(float f, unsigned short& h, unsigned short& l) {
    h = f2b(f);
    float hf = __uint_as_float((unsigned int)h << 16);
    l = f2b(f - hf);
}

// ---------------------------------------------------------------------------
// Pre-split weights into fragment-contiguous layout + init bucket cursors.
// Element W^T[ncol][kk] -> Wf[(((kk>>5)*16+(ncol>>4))*64 + ((kk>>3)&3)*16 + (ncol&15))*8 + (kk&7)]
// so each consumer fragment load is 64 lanes x consecutive 16B = 1KB coalesced.
__global__ __launch_bounds__(256) void wsplit_kernel(const float* __restrict__ W1, const float* __restrict__ b1,
                                                     const float* __restrict__ W2, const float* __restrict__ b2,
                                                     unsigned short* __restrict__ Wfh, unsigned short* __restrict__ Wfl,
                                                     float* __restrict__ bc, int* __restrict__ bktCur) {
    int n = blockIdx.x;    // 0..255 combined output column
    int k = threadIdx.x;   // 0..255 input channel
    if (n < 2) {
        int i = n * 256 + k;
        bktCur[i] = i * BKT_CAP;
    }
    float w = (n < OUT_CH) ? W2[k * OUT_CH + n] : W1[k * OUT_CH + (n - OUT_CH)];
    unsigned short h, l;
    split2(w, h, l);
    int idx = (((k >> 5) * 16 + (n >> 4)) * 64 + ((k >> 3) & 3) * 16 + (n & 15)) * 8 + (k & 7);
    Wfh[idx] = h;
    Wfl[idx] = l;
    if (k == 0) bc[n] = (n < OUT_CH) ? b2[n] : b1[n - OUT_CH];
}

// ---------------------------------------------------------------------------
// part body: partition edges into fixed-capacity bucket windows as packed 4B
// keys: key = (dstLow<<17) | src. uint4-vectorized edge streams; 256 blocks
// -> ~49 edges per (block,bucket) run (~196B, full cache lines) and only
// 256 serialized claim atomics per bktCur int.
__device__ __forceinline__ void part_body(char* smem, const int* __restrict__ row, const int* __restrict__ col,
                                          int* __restrict__ bktCur, unsigned int* __restrict__ pairs,
                                          int E, int NBKT, int nPart, int pb) {
    int* lh   = (int*)smem;         // [512]
    int* lcur = lh + 512;           // [512]
    int t = threadIdx.x;
    lh[t] = 0; lh[t + 256] = 0;
    __syncthreads();
    int tile = (E + nPart - 1) / nPart;
    int e0 = pb * tile;
    int e1 = min(E, e0 + tile);
    if ((tile & 3) == 0 && (e0 & 3) == 0 && e1 == e0 + tile) {
        const uint4* c4 = (const uint4*)(col + e0);
        const uint4* r4 = (const uint4*)(row + e0);
        int n4 = tile >> 2;
        for (int i = t; i < n4; i += 256) {
            uint4 c = c4[i];
            atomicAdd(&lh[c.x >> BKT_SH], 1);
            atomicAdd(&lh[c.y >> BKT_SH], 1);
            atomicAdd(&lh[c.z >> BKT_SH], 1);
            atomicAdd(&lh[c.w >> BKT_SH], 1);
        }
        __syncthreads();
        for (int b = t; b < 512; b += 256) {
            int c = (b < NBKT) ? lh[b] : 0;
            lcur[b] = (c > 0) ? atomicAdd(&bktCur[b], c) : 0;
        }
        __syncthreads();
        for (int i = t; i < n4; i += 256) {
            uint4 c = c4[i];
            uint4 r = r4[i];
            int p0 = atomicAdd(&lcur[c.x >> BKT_SH], 1); pairs[p0] = ((c.x & 255u) << 17) | r.x;
            int p1 = atomicAdd(&lcur[c.y >> BKT_SH], 1); pairs[p1] = ((c.y & 255u) << 17) | r.y;
            int p2 = atomicAdd(&lcur[c.z >> BKT_SH], 1); pairs[p2] = ((c.z & 255u) << 17) | r.z;
            int p3 = atomicAdd(&lcur[c.w >> BKT_SH], 1); pairs[p3] = ((c.w & 255u) << 17) | r.w;
        }
    } else {
        for (int i = e0 + t; i < e1; i += 256)
            atomicAdd(&lh[col[i] >> BKT_SH], 1);
        __syncthreads();
        for (int b = t; b < 512; b += 256) {
            int c = (b < NBKT) ? lh[b] : 0;
            lcur[b] = (c > 0) ? atomicAdd(&bktCur[b], c) : 0;
        }
        __syncthreads();
        for (int i = e0 + t; i < e1; i += 256) {
            int c = col[i];
            int pos = atomicAdd(&lcur[c >> BKT_SH], 1);
            pairs[pos] = ((unsigned int)(c & 255) << 17) | (unsigned int)row[i];
        }
    }
}

// ---------------------------------------------------------------------------
// csr body: per-node count + scan -> offs/deg/dinv, then scatter into the
// bucket's contiguous csr window (L2-local).
__device__ __forceinline__ void csr_body(char* smem, const unsigned int* __restrict__ pairs,
                                         const int* __restrict__ bktCur,
                                         int* __restrict__ csr, int* __restrict__ offs,
                                         int* __restrict__ deg, float* __restrict__ dinv,
                                         int N, int b) {
    int* s    = (int*)smem;           // [256]
    int* nc   = (int*)(smem + 1024);  // [256]
    int* ncur = (int*)(smem + 2048);  // [256]
    int t = threadIdx.x;
    int base = b * BKT_CAP;
    int cnt = bktCur[b] - base;

    nc[t] = 0;
    __syncthreads();
    for (int i = t; i < cnt; i += 256)
        atomicAdd(&nc[pairs[base + i] >> 17], 1);
    __syncthreads();
    int dv = nc[t];
    s[t] = dv;
    __syncthreads();
    for (int o = 1; o < 256; o <<= 1) {
        int u = (t >= o) ? s[t - o] : 0;
        __syncthreads();
        s[t] += u;
        __syncthreads();
    }
    int rel = s[t] - dv;  // exclusive
    int n = (b << BKT_SH) + t;
    if (n < N) {
        offs[n] = base + rel;
        deg[n] = dv;
        dinv[n] = 1.0f / sqrtf((float)dv + 1.0f);
    }
    ncur[t] = rel;
    __syncthreads();
    for (int i = t; i < cnt; i += 256) {
        unsigned int k = pairs[base + i];
        int node = k >> 17;
        int pos = atomicAdd(&ncur[node], 1);
        csr[base + pos] = (int)(k & 0x1FFFF);
    }
}

// ---------------------------------------------------------------------------
// gemm body: MFMA bf16 GEMM, 32 rows/block, 4 waves (64-col strip each, 2
// row-tiles x 4 col-tiles). W fragments are coalesced 1KB loads (see wsplit).
// 17KB LDS -> 8 blocks/CU so co-scheduled part/csr latency hides under MFMA.
// gb[n][0..127] = bf16(1.8/||h_n|| * h[n][c]), gb[n][128..255] = bf16(y[n][c]).
#define XPAD 264  // 256 + 8 bf16 pad
#define GEMM_SMEM (GT_M * XPAD * 2 + 2 * GT_M * 4)   // 17152B
__device__ __forceinline__ void gemm_body(char* smem, const float* __restrict__ x,
                                          const unsigned short* __restrict__ Wfh,
                                          const unsigned short* __restrict__ Wfl,
                                          const float* __restrict__ bc,
                                          unsigned short* __restrict__ gb, int blockRow, int N) {
    unsigned short* xh = (unsigned short*)smem;             // [GT_M*XPAD]
    float* sn = (float*)(smem + GT_M * XPAD * sizeof(unsigned short));  // [2*GT_M]

    int t = threadIdx.x;
    size_t row0 = (size_t)blockRow * GT_M;

    const float4* xg = (const float4*)(x + row0 * IN_CH);
#pragma unroll
    for (int i = 0; i < 8; i++) {
        int f4 = t + i * 256;        // 0..2047
        int row = f4 >> 6;
        int c4 = (f4 & 63) * 4;
        uint2 hw = {0u, 0u};
        if (row0 + row < (size_t)N) {
            float4 v = xg[f4];
            hw.x = (unsigned int)f2b(v.x) | ((unsigned int)f2b(v.y) << 16);
            hw.y = (unsigned int)f2b(v.z) | ((unsigned int)f2b(v.w) << 16);
        }
        *(uint2*)&xh[row * XPAD + c4] = hw;
    }
    __syncthreads();

    int lane = t & 63;
    int wv = t >> 6;
    int lr = lane & 15;
    int lk = (lane >> 4) * 8;

    f32x4 acc[2][4];
#pragma unroll
    for (int rt = 0; rt < 2; rt++)
#pragma unroll
        for (int ct = 0; ct < 4; ct++) acc[rt][ct] = (f32x4){0.f, 0.f, 0.f, 0.f};

#pragma unroll
    for (int kt = 0; kt < 8; kt++) {
        int k0 = kt * 32;
        bf16x8 bh[4], bl[4];
#pragma unroll
        for (int ct = 0; ct < 4; ct++) {
            int fidx = ((kt * 16 + wv * 4 + ct) * 64 + lane) * 8;
            bh[ct] = *(const bf16x8*)&Wfh[fidx];
            bl[ct] = *(const bf16x8*)&Wfl[fidx];
        }
        bf16x8 ah[2];
#pragma unroll
        for (int rt = 0; rt < 2; rt++) {
            int idx = (rt * 16 + lr) * XPAD + k0 + lk;
            ah[rt] = *(const bf16x8*)&xh[idx];
        }
#pragma unroll
        for (int rt = 0; rt < 2; rt++)
#pragma unroll
            for (int ct = 0; ct < 4; ct++) {
                acc[rt][ct] = __builtin_amdgcn_mfma_f32_16x16x32_bf16(ah[rt], bh[ct], acc[rt][ct], 0, 0, 0);
                acc[rt][ct] = __builtin_amdgcn_mfma_f32_16x16x32_bf16(ah[rt], bl[ct], acc[rt][ct], 0, 0, 0);
            }
    }
    __syncthreads();

    float bcv[4];
#pragma unroll
    for (int ct = 0; ct < 4; ct++) bcv[ct] = bc[wv * 64 + ct * 16 + lr];
#pragma unroll
    for (int rt = 0; rt < 2; rt++)
#pragma unroll
        for (int ct = 0; ct < 4; ct++)
#pragma unroll
            for (int j = 0; j < 4; j++) acc[rt][ct][j] += bcv[ct];

    if (wv < 2) {
        float nr[2][4];
#pragma unroll
        for (int rt = 0; rt < 2; rt++)
#pragma unroll
            for (int j = 0; j < 4; j++) {
                float sum = 0.f;
#pragma unroll
                for (int ct = 0; ct < 4; ct++) sum += acc[rt][ct][j] * acc[rt][ct][j];
                nr[rt][j] = sum;
            }
#pragma unroll
        for (int o = 1; o < 16; o <<= 1)
#pragma unroll
            for (int rt = 0; rt < 2; rt++)
#pragma unroll
                for (int j = 0; j < 4; j++) nr[rt][j] += __shfl_xor(nr[rt][j], o);
        if (lr == 0) {
#pragma unroll
            for (int rt = 0; rt < 2; rt++)
#pragma unroll
                for (int j = 0; j < 4; j++)
                    sn[wv * GT_M + rt * 16 + (lane >> 4) * 4 + j] = nr[rt][j];
        }
    }
    __syncthreads();

#pragma unroll
    for (int rt = 0; rt < 2; rt++) {
#pragma unroll
        for (int j = 0; j < 4; j++) {
            int rl = rt * 16 + (lane >> 4) * 4 + j;
            if (row0 + rl >= (size_t)N) continue;
            float sf;
            if (wv < 2) {
                float n2 = sn[rl] + sn[GT_M + rl];
                sf = SCALE / fmaxf(sqrtf(n2), 1e-12f);
            } else {
                sf = 1.0f;
            }
            size_t base = (row0 + rl) * 256;
#pragma unroll
            for (int ct = 0; ct < 4; ct++) {
                int col = wv * 64 + ct * 16 + lr;
                gb[base + col] = f2b(acc[rt][ct][j] * sf);
            }
        }
    }
}

// ---------------------------------------------------------------------------
// K1: part INTERLEAVED with gemm rows A (proportional block-ID mapping so
// every CU holds a mix; latency-bound part hides under gemm compute).
__global__ __launch_bounds__(256) void k1_part_gemm(const int* __restrict__ row, const int* __restrict__ col,
                                                    int* __restrict__ bktCur, unsigned int* __restrict__ pairs,
                                                    int E, int NBKT, int nPart, int total,
                                                    const float* __restrict__ x,
                                                    const unsigned short* __restrict__ Wfh,
                                                    const unsigned short* __restrict__ Wfl,
                                                    const float* __restrict__ bc,
                                                    unsigned short* __restrict__ gb, int N) {
    __shared__ __align__(16) char smem[GEMM_SMEM];
    int b = (int)blockIdx.x;
    int before = (int)(((long long)b * nPart) / total);
    int after  = (int)(((long long)(b + 1) * nPart) / total);
    if (after > before) part_body(smem, row, col, bktCur, pairs, E, NBKT, nPart, before);
    else gemm_body(smem, x, Wfh, Wfl, bc, gb, b - before, N);
}

// K2: csr INTERLEAVED with gemm rows B.
__global__ __launch_bounds__(256) void k2_csr_gemm(const unsigned int* __restrict__ pairs,
                                                   const int* __restrict__ bktCur,
                                                   int* __restrict__ csr, int* __restrict__ offs,
                                                   int* __restrict__ deg, float* __restrict__ dinv,
                                                   int N, int nCsr, int total, int gemmRowBase,
                                                   const float* __restrict__ x,
                                                   const unsigned short* __restrict__ Wfh,
                                                   const unsigned short* __restrict__ Wfl,
                                                   const float* __restrict__ bc,
                                                   unsigned short* __restrict__ gb) {
    __shared__ __align__(16) char smem[GEMM_SMEM];
    int b = (int)blockIdx.x;
    int before = (int)(((long long)b * nCsr) / total);
    int after  = (int)(((long long)(b + 1) * nCsr) / total);
    if (after > before) csr_body(smem, pairs, bktCur, csr, offs, deg, dinv, N, before);
    else gemm_body(smem, x, Wfh, Wfl, bc, gb, gemmRowBase + (b - before), N);
}

// ---------------------------------------------------------------------------
// Fused gather-propagate, both branches. One node per 64-lane wave; two
// 32-lane halves walk alternating edges of the same list; lane owns 16B
// chunk (l&31) of the 512B gb row. Per-edge dinv[src] weighting (broadcast
// load, 400KB L2-resident). Halves combine via shfl_xor(32).
// out[n] = dinv[n] * sum_{s in n + nbrs} dinv[s] * f[s]
__global__ __launch_bounds__(256) void gather_kernel(const uint4* __restrict__ gp,
                                                     const int* __restrict__ offs, const int* __restrict__ deg,
                                                     const int* __restrict__ csr, const float* __restrict__ dinv,
                                                     float* __restrict__ outh, float* __restrict__ outx, int N) {
    int t = threadIdx.x;
    int n = (blockIdx.x << 2) + (t >> 6);   // 4 waves per block, 1 node per wave
    if (n >= N) return;
    int l = t & 63;
    int half = l >> 5;   // which edge-subsequence this half-wave walks
    int cl = l & 31;     // 16B chunk index within the row

    float a0 = 0.f, a1 = 0.f, a2 = 0.f, a3 = 0.f, a4 = 0.f, a5 = 0.f, a6 = 0.f, a7 = 0.f;
    auto accumw = [&](uint4 w, float ds) {
        a0 += blo(w.x) * ds; a1 += bhi(w.x) * ds;
        a2 += blo(w.y) * ds; a3 += bhi(w.y) * ds;
        a4 += blo(w.z) * ds; a5 += bhi(w.z) * ds;
        a6 += blo(w.w) * ds; a7 += bhi(w.w) * ds;
    };

    float dn = dinv[n];
    // self loop (half 0 only; combined later)
    if (half == 0) accumw(gp[(size_t)n * 32 + cl], dn);

    int s0 = offs[n];
    int e1 = s0 + deg[n];
    int e = s0 + half;
    for (; e + 2 < e1; e += 4) {
        int sa = csr[e];
        int sb = csr[e + 2];
        float da = dinv[sa];
        float db = dinv[sb];
        uint4 wa = gp[(size_t)sa * 32 + cl];
        uint4 wb = gp[(size_t)sb * 32 + cl];
        accumw(wa, da); accumw(wb, db);
    }
    for (; e < e1; e += 2) {
        int sa = csr[e];
        accumw(gp[(size_t)sa * 32 + cl], dinv[sa]);
    }

    // combine the two halves (channels match: lane l <-> l^32)
    a0 += __shfl_xor(a0, 32);
    a1 += __shfl_xor(a1, 32);
    a2 += __shfl_xor(a2, 32);
    a3 += __shfl_xor(a3, 32);
    a4 += __shfl_xor(a4, 32);
    a5 += __shfl_xor(a5, 32);
    a6 += __shfl_xor(a6, 32);
    a7 += __shfl_xor(a7, 32);

    if (half == 0) {
        float4 v0 = {a0 * dn, a1 * dn, a2 * dn, a3 * dn};
        float4 v1 = {a4 * dn, a5 * dn, a6 * dn, a7 * dn};
        if (cl < 16) {
            float* o = &outh[(size_t)n * OUT_CH + cl * 8];
            *(float4*)o = v0;
            *(float4*)(o + 4) = v1;
        } else {
            float* o = &outx[(size_t)n * OUT_CH + (cl - 16) * 8];
            *(float4*)o = v0;
            *(float4*)(o + 4) = v1;
        }
    }
}

// ---------------------------------------------------------------------------
extern "C" void kernel_launch(void* const* d_in, const int* in_sizes, int n_in,
                              void* d_out, int out_size, void* d_ws, size_t ws_size,
                              hipStream_t stream) {
    const float* x   = (const float*)d_in[0];
    const int*   ei  = (const int*)d_in[1];   // int32 (JAX x64-disabled)
    const float* W1  = (const float*)d_in[2];
    const float* b1  = (const float*)d_in[3];
    const float* W2  = (const float*)d_in[4];
    const float* b2  = (const float*)d_in[5];

    const int N = in_sizes[0] / IN_CH;   // 100000
    const int E = in_sizes[1] / 2;       // 3200000
    const int NBKT = (N + 255) >> BKT_SH;  // 391

    float* outh = (float*)d_out;                      // branch 2 result (h) first
    float* outx = outh + (size_t)N * OUT_CH;          // branch 1 result (x_)

    // Workspace layout (pairs and gb both live concurrently)
    char* p = (char*)d_ws;
    auto take = [&](size_t bytes) {
        char* q = p;
        p += (bytes + 255) & ~(size_t)255;
        return q;
    };
    int*   deg     = (int*)take((size_t)N * sizeof(int));
    float* dinv    = (float*)take((size_t)N * sizeof(float));
    int*   offs    = (int*)take((size_t)N * sizeof(int));
    int*   bktCur  = (int*)take(512 * sizeof(int));
    float* bc      = (float*)take(256 * sizeof(float));
    unsigned short* Wfh = (unsigned short*)take(256 * 256 * sizeof(unsigned short));
    unsigned short* Wfl = (unsigned short*)take(256 * 256 * sizeof(unsigned short));
    int*   csr     = (int*)take((size_t)NBKT * BKT_CAP * sizeof(int));
    unsigned int* pairs = (unsigned int*)take((size_t)NBKT * BKT_CAP * sizeof(unsigned int));
    unsigned short* gb = (unsigned short*)take((size_t)N * 256 * sizeof(unsigned short));

    const int* erow = ei;
    const int* ecol = ei + E;

    const int nPart = 256;                          // tile = 12500 (uint4-aligned); 256 claim atomics/int
    const int gemmBlocks = (N + GT_M - 1) / GT_M;   // 3125
    const int gemmA = (gemmBlocks + 1) / 2;         // 1563 (K1)
    const int gemmB = gemmBlocks - gemmA;           // 1562 (K2)
    const int totK1 = nPart + gemmA;                // 1819
    const int totK2 = NBKT + gemmB;                 // 1953

    wsplit_kernel<<<256, 256, 0, stream>>>(W1, b1, W2, b2, Wfh, Wfl, bc, bktCur);
    k1_part_gemm<<<totK1, 256, 0, stream>>>(erow, ecol, bktCur, pairs, E, NBKT, nPart, totK1,
                                            x, Wfh, Wfl, bc, gb, N);
    k2_csr_gemm<<<totK2, 256, 0, stream>>>(pairs, bktCur, csr, offs, deg, dinv, N, NBKT, totK2, gemmA,
                                           x, Wfh, Wfl, bc, gb);
    gather_kernel<<<(N + 3) / 4, 256, 0, stream>>>((const uint4*)gb, offs, deg, csr, dinv, outh, outx, N);
}

// Round 19
// 393.005 us; speedup vs baseline: 1.0161x; 1.0161x over previous
//
#include <hip/hip_runtime.h>

// Problem constants (from reference)
#define IN_CH   256
#define OUT_CH  128
#define SCALE   1.8f
#define GT_M    64      // GEMM rows per block (4 row-tiles per wave)
#define BKT_SH  8       // 256 nodes per bucket
#define BKT_CAP 9216    // fixed bucket window capacity (mean 8192 + 11 sigma)

using bf16x8 = __attribute__((ext_vector_type(8))) short;   // 8 bf16 = 4 VGPR
using f32x4  = __attribute__((ext_vector_type(4))) float;

// bf16 helpers (bit-level, round-to-nearest-even on pack)
__device__ __forceinline__ float blo(unsigned int w) { return __uint_as_float(w << 16); }
__device__ __forceinline__ float bhi(unsigned int w) { return __uint_as_float(w & 0xffff0000u); }
__device__ __forceinline__ unsigned short f2b(float f) {
    unsigned int u = __float_as_uint(f);
    u += 0x7fffu + ((u >> 16) & 1u);
    return (unsigned short)(u >> 16);
}
// split float -> hi bf16 + lo bf16 (residual)
__device__ __forceinline__ void split2(float f, unsigned short& h, unsigned short& l) {
    h = f2b(f);
    float hf = __uint_as_float((unsigned int)h << 16);
    l = f2b(f - hf);
}

// ---------------------------------------------------------------------------
// Pre-split weights into fragment-contiguous layout + init bucket cursors.
// Element W^T[ncol][kk] -> Wf[(((kk>>5)*16+(ncol>>4))*64 + ((kk>>3)&3)*16 + (ncol&15))*8 + (kk&7)]
// so each consumer fragment load is 64 lanes x consecutive 16B = 1KB coalesced.
__global__ __launch_bounds__(256) void wsplit_kernel(const float* __restrict__ W1, const float* __restrict__ b1,
                                                     const float* __restrict__ W2, const float* __restrict__ b2,
                                                     unsigned short* __restrict__ Wfh, unsigned short* __restrict__ Wfl,
                                                     float* __restrict__ bc, int* __restrict__ bktCur) {
    int n = blockIdx.x;    // 0..255 combined output column
    int k = threadIdx.x;   // 0..255 input channel
    if (n < 2) {
        int i = n * 256 + k;
        bktCur[i] = i * BKT_CAP;
    }
    float w = (n < OUT_CH) ? W2[k * OUT_CH + n] : W1[k * OUT_CH + (n - OUT_CH)];
    unsigned short h, l;
    split2(w, h, l);
    int idx = (((k >> 5) * 16 + (n >> 4)) * 64 + ((k >> 3) & 3) * 16 + (n & 15)) * 8 + (k & 7);
    Wfh[idx] = h;
    Wfl[idx] = l;
    if (k == 0) bc[n] = (n < OUT_CH) ? b2[n] : b1[n - OUT_CH];
}

// ---------------------------------------------------------------------------
// part: partition edges into fixed-capacity bucket windows as packed 4B keys:
// key = (dstLow<<17) | src. uint4-vectorized edge streams (4/thread-iter).
__global__ __launch_bounds__(256) void part_kernel(const int* __restrict__ row, const int* __restrict__ col,
                                                   int* __restrict__ bktCur, unsigned int* __restrict__ pairs,
                                                   int E, int NBKT, int nPart) {
    __shared__ int lh[512];
    __shared__ int lcur[512];
    int pb = (int)blockIdx.x;
    int t = threadIdx.x;
    lh[t] = 0; lh[t + 256] = 0;
    __syncthreads();
    int tile = (E + nPart - 1) / nPart;
    int e0 = pb * tile;
    int e1 = min(E, e0 + tile);
    if ((tile & 3) == 0 && (e0 & 3) == 0 && e1 == e0 + tile) {
        const uint4* c4 = (const uint4*)(col + e0);
        const uint4* r4 = (const uint4*)(row + e0);
        int n4 = tile >> 2;
        for (int i = t; i < n4; i += 256) {
            uint4 c = c4[i];
            atomicAdd(&lh[c.x >> BKT_SH], 1);
            atomicAdd(&lh[c.y >> BKT_SH], 1);
            atomicAdd(&lh[c.z >> BKT_SH], 1);
            atomicAdd(&lh[c.w >> BKT_SH], 1);
        }
        __syncthreads();
        for (int b = t; b < 512; b += 256) {
            int c = (b < NBKT) ? lh[b] : 0;
            lcur[b] = (c > 0) ? atomicAdd(&bktCur[b], c) : 0;
        }
        __syncthreads();
        for (int i = t; i < n4; i += 256) {
            uint4 c = c4[i];
            uint4 r = r4[i];
            int p0 = atomicAdd(&lcur[c.x >> BKT_SH], 1); pairs[p0] = ((c.x & 255u) << 17) | r.x;
            int p1 = atomicAdd(&lcur[c.y >> BKT_SH], 1); pairs[p1] = ((c.y & 255u) << 17) | r.y;
            int p2 = atomicAdd(&lcur[c.z >> BKT_SH], 1); pairs[p2] = ((c.z & 255u) << 17) | r.z;
            int p3 = atomicAdd(&lcur[c.w >> BKT_SH], 1); pairs[p3] = ((c.w & 255u) << 17) | r.w;
        }
    } else {
        for (int i = e0 + t; i < e1; i += 256)
            atomicAdd(&lh[col[i] >> BKT_SH], 1);
        __syncthreads();
        for (int b = t; b < 512; b += 256) {
            int c = (b < NBKT) ? lh[b] : 0;
            lcur[b] = (c > 0) ? atomicAdd(&bktCur[b], c) : 0;
        }
        __syncthreads();
        for (int i = e0 + t; i < e1; i += 256) {
            int c = col[i];
            int pos = atomicAdd(&lcur[c >> BKT_SH], 1);
            pairs[pos] = ((unsigned int)(c & 255) << 17) | (unsigned int)row[i];
        }
    }
}

// ---------------------------------------------------------------------------
// csr: per-bucket per-node count + scan -> offs/deg/dinv, then scatter into
// the bucket's contiguous csr window (L2-local).
__global__ __launch_bounds__(256) void csr_kernel(const unsigned int* __restrict__ pairs,
                                                  const int* __restrict__ bktCur,
                                                  int* __restrict__ csr, int* __restrict__ offs,
                                                  int* __restrict__ deg, float* __restrict__ dinv,
                                                  int N) {
    __shared__ int s[256];
    __shared__ int nc[256];
    __shared__ int ncur[256];
    int b = (int)blockIdx.x;
    int t = threadIdx.x;
    int base = b * BKT_CAP;
    int cnt = bktCur[b] - base;

    nc[t] = 0;
    __syncthreads();
    for (int i = t; i < cnt; i += 256)
        atomicAdd(&nc[pairs[base + i] >> 17], 1);
    __syncthreads();
    int dv = nc[t];
    s[t] = dv;
    __syncthreads();
    for (int o = 1; o < 256; o <<= 1) {
        int u = (t >= o) ? s[t - o] : 0;
        __syncthreads();
        s[t] += u;
        __syncthreads();
    }
    int rel = s[t] - dv;  // exclusive
    int n = (b << BKT_SH) + t;
    if (n < N) {
        offs[n] = base + rel;
        deg[n] = dv;
        dinv[n] = 1.0f / sqrtf((float)dv + 1.0f);
    }
    ncur[t] = rel;
    __syncthreads();
    for (int i = t; i < cnt; i += 256) {
        unsigned int k = pairs[base + i];
        int node = k >> 17;
        int pos = atomicAdd(&ncur[node], 1);
        csr[base + pos] = (int)(k & 0x1FFFF);
    }
}

// ---------------------------------------------------------------------------
// gemm: MFMA bf16 GEMM, 64 rows/block, 4 waves (64-col strip each, 4
// row-tiles x 4 col-tiles). W fragments are coalesced 1KB loads (see wsplit);
// each fragment reused across 4 row-tiles. + bias + rownorm(h) + bf16 pack.
// gb[n][0..127] = bf16(1.8/||h_n|| * h[n][c]), gb[n][128..255] = bf16(y[n][c]).
#define XPAD 264  // 256 + 8 bf16 pad
__global__ __launch_bounds__(256) void gemm_kernel(const float* __restrict__ x,
                                                   const unsigned short* __restrict__ Wfh,
                                                   const unsigned short* __restrict__ Wfl,
                                                   const float* __restrict__ bc,
                                                   unsigned short* __restrict__ gb, int N) {
    __shared__ unsigned short xh[GT_M * XPAD];
    __shared__ float sn[2 * GT_M];

    int t = threadIdx.x;
    size_t row0 = (size_t)blockIdx.x * GT_M;

    const float4* xg = (const float4*)(x + row0 * IN_CH);
#pragma unroll
    for (int i = 0; i < 16; i++) {
        int f4 = t + i * 256;        // 0..4095
        int row = f4 >> 6;
        int c4 = (f4 & 63) * 4;
        uint2 hw = {0u, 0u};
        if (row0 + row < (size_t)N) {
            float4 v = xg[f4];
            hw.x = (unsigned int)f2b(v.x) | ((unsigned int)f2b(v.y) << 16);
            hw.y = (unsigned int)f2b(v.z) | ((unsigned int)f2b(v.w) << 16);
        }
        *(uint2*)&xh[row * XPAD + c4] = hw;
    }
    __syncthreads();

    int lane = t & 63;
    int wv = t >> 6;
    int lr = lane & 15;
    int lk = (lane >> 4) * 8;

    f32x4 acc[4][4];
#pragma unroll
    for (int rt = 0; rt < 4; rt++)
#pragma unroll
        for (int ct = 0; ct < 4; ct++) acc[rt][ct] = (f32x4){0.f, 0.f, 0.f, 0.f};

#pragma unroll
    for (int kt = 0; kt < 8; kt++) {
        int k0 = kt * 32;
        bf16x8 bh[4], bl[4];
#pragma unroll
        for (int ct = 0; ct < 4; ct++) {
            int fidx = ((kt * 16 + wv * 4 + ct) * 64 + lane) * 8;
            bh[ct] = *(const bf16x8*)&Wfh[fidx];
            bl[ct] = *(const bf16x8*)&Wfl[fidx];
        }
        bf16x8 ah[4];
#pragma unroll
        for (int rt = 0; rt < 4; rt++) {
            int idx = (rt * 16 + lr) * XPAD + k0 + lk;
            ah[rt] = *(const bf16x8*)&xh[idx];
        }
#pragma unroll
        for (int rt = 0; rt < 4; rt++)
#pragma unroll
            for (int ct = 0; ct < 4; ct++) {
                acc[rt][ct] = __builtin_amdgcn_mfma_f32_16x16x32_bf16(ah[rt], bh[ct], acc[rt][ct], 0, 0, 0);
                acc[rt][ct] = __builtin_amdgcn_mfma_f32_16x16x32_bf16(ah[rt], bl[ct], acc[rt][ct], 0, 0, 0);
            }
    }
    __syncthreads();

    float bcv[4];
#pragma unroll
    for (int ct = 0; ct < 4; ct++) bcv[ct] = bc[wv * 64 + ct * 16 + lr];
#pragma unroll
    for (int rt = 0; rt < 4; rt++)
#pragma unroll
        for (int ct = 0; ct < 4; ct++)
#pragma unroll
            for (int j = 0; j < 4; j++) acc[rt][ct][j] += bcv[ct];

    if (wv < 2) {
        float nr[4][4];
#pragma unroll
        for (int rt = 0; rt < 4; rt++)
#pragma unroll
            for (int j = 0; j < 4; j++) {
                float sum = 0.f;
#pragma unroll
                for (int ct = 0; ct < 4; ct++) sum += acc[rt][ct][j] * acc[rt][ct][j];
                nr[rt][j] = sum;
            }
#pragma unroll
        for (int o = 1; o < 16; o <<= 1)
#pragma unroll
            for (int rt = 0; rt < 4; rt++)
#pragma unroll
                for (int j = 0; j < 4; j++) nr[rt][j] += __shfl_xor(nr[rt][j], o);
        if (lr == 0) {
#pragma unroll
            for (int rt = 0; rt < 4; rt++)
#pragma unroll
                for (int j = 0; j < 4; j++)
                    sn[wv * GT_M + rt * 16 + (lane >> 4) * 4 + j] = nr[rt][j];
        }
    }
    __syncthreads();

#pragma unroll
    for (int rt = 0; rt < 4; rt++) {
#pragma unroll
        for (int j = 0; j < 4; j++) {
            int rl = rt * 16 + (lane >> 4) * 4 + j;
            if (row0 + rl >= (size_t)N) continue;
            float sf;
            if (wv < 2) {
                float n2 = sn[rl] + sn[GT_M + rl];
                sf = SCALE / fmaxf(sqrtf(n2), 1e-12f);
            } else {
                sf = 1.0f;
            }
            size_t base = (row0 + rl) * 256;
#pragma unroll
            for (int ct = 0; ct < 4; ct++) {
                int col = wv * 64 + ct * 16 + lr;
                gb[base + col] = f2b(acc[rt][ct][j] * sf);
            }
        }
    }
}

// ---------------------------------------------------------------------------
// Fused gather-propagate, both branches. One node per 64-lane wave; two
// 32-lane halves walk alternating edges of the same list; lane owns 16B
// chunk (l&31) of the 512B gb row. Per-edge dinv[src] weighting (broadcast
// load, 400KB L2-resident). Halves combine via shfl_xor(32).
// out[n] = dinv[n] * sum_{s in n + nbrs} dinv[s] * f[s]
__global__ __launch_bounds__(256) void gather_kernel(const uint4* __restrict__ gp,
                                                     const int* __restrict__ offs, const int* __restrict__ deg,
                                                     const int* __restrict__ csr, const float* __restrict__ dinv,
                                                     float* __restrict__ outh, float* __restrict__ outx, int N) {
    int t = threadIdx.x;
    int n = (blockIdx.x << 2) + (t >> 6);   // 4 waves per block, 1 node per wave
    if (n >= N) return;
    int l = t & 63;
    int half = l >> 5;   // which edge-subsequence this half-wave walks
    int cl = l & 31;     // 16B chunk index within the row

    float a0 = 0.f, a1 = 0.f, a2 = 0.f, a3 = 0.f, a4 = 0.f, a5 = 0.f, a6 = 0.f, a7 = 0.f;
    auto accumw = [&](uint4 w, float ds) {
        a0 += blo(w.x) * ds; a1 += bhi(w.x) * ds;
        a2 += blo(w.y) * ds; a3 += bhi(w.y) * ds;
        a4 += blo(w.z) * ds; a5 += bhi(w.z) * ds;
        a6 += blo(w.w) * ds; a7 += bhi(w.w) * ds;
    };

    float dn = dinv[n];
    // self loop (half 0 only; combined later)
    if (half == 0) accumw(gp[(size_t)n * 32 + cl], dn);

    int s0 = offs[n];
    int e1 = s0 + deg[n];
    int e = s0 + half;
    for (; e + 2 < e1; e += 4) {
        int sa = csr[e];
        int sb = csr[e + 2];
        float da = dinv[sa];
        float db = dinv[sb];
        uint4 wa = gp[(size_t)sa * 32 + cl];
        uint4 wb = gp[(size_t)sb * 32 + cl];
        accumw(wa, da); accumw(wb, db);
    }
    for (; e < e1; e += 2) {
        int sa = csr[e];
        accumw(gp[(size_t)sa * 32 + cl], dinv[sa]);
    }

    // combine the two halves (channels match: lane l <-> l^32)
    a0 += __shfl_xor(a0, 32);
    a1 += __shfl_xor(a1, 32);
    a2 += __shfl_xor(a2, 32);
    a3 += __shfl_xor(a3, 32);
    a4 += __shfl_xor(a4, 32);
    a5 += __shfl_xor(a5, 32);
    a6 += __shfl_xor(a6, 32);
    a7 += __shfl_xor(a7, 32);

    if (half == 0) {
        float4 v0 = {a0 * dn, a1 * dn, a2 * dn, a3 * dn};
        float4 v1 = {a4 * dn, a5 * dn, a6 * dn, a7 * dn};
        if (cl < 16) {
            float* o = &outh[(size_t)n * OUT_CH + cl * 8];
            *(float4*)o = v0;
            *(float4*)(o + 4) = v1;
        } else {
            float* o = &outx[(size_t)n * OUT_CH + (cl - 16) * 8];
            *(float4*)o = v0;
            *(float4*)(o + 4) = v1;
        }
    }
}

// ---------------------------------------------------------------------------
extern "C" void kernel_launch(void* const* d_in, const int* in_sizes, int n_in,
                              void* d_out, int out_size, void* d_ws, size_t ws_size,
                              hipStream_t stream) {
    const float* x   = (const float*)d_in[0];
    const int*   ei  = (const int*)d_in[1];   // int32 (JAX x64-disabled)
    const float* W1  = (const float*)d_in[2];
    const float* b1  = (const float*)d_in[3];
    const float* W2  = (const float*)d_in[4];
    const float* b2  = (const float*)d_in[5];

    const int N = in_sizes[0] / IN_CH;   // 100000
    const int E = in_sizes[1] / 2;       // 3200000
    const int NBKT = (N + 255) >> BKT_SH;  // 391

    float* outh = (float*)d_out;                      // branch 2 result (h) first
    float* outx = outh + (size_t)N * OUT_CH;          // branch 1 result (x_)

    // Workspace layout
    char* p = (char*)d_ws;
    auto take = [&](size_t bytes) {
        char* q = p;
        p += (bytes + 255) & ~(size_t)255;
        return q;
    };
    int*   deg     = (int*)take((size_t)N * sizeof(int));
    float* dinv    = (float*)take((size_t)N * sizeof(float));
    int*   offs    = (int*)take((size_t)N * sizeof(int));
    int*   bktCur  = (int*)take(512 * sizeof(int));
    float* bc      = (float*)take(256 * sizeof(float));
    unsigned short* Wfh = (unsigned short*)take(256 * 256 * sizeof(unsigned short));
    unsigned short* Wfl = (unsigned short*)take(256 * 256 * sizeof(unsigned short));
    int*   csr     = (int*)take((size_t)NBKT * BKT_CAP * sizeof(int));
    unsigned int* pairs = (unsigned int*)take((size_t)NBKT * BKT_CAP * sizeof(unsigned int));
    unsigned short* gb = (unsigned short*)take((size_t)N * 256 * sizeof(unsigned short));

    const int* erow = ei;
    const int* ecol = ei + E;

    const int nPart = 500;   // tile = 6400 (uint4-aligned)

    // Fully serial pipeline: direct per-stage attribution, no co-residency
    // interference (L2 pollution / LDS-occupancy coupling between bodies).
    wsplit_kernel<<<256, 256, 0, stream>>>(W1, b1, W2, b2, Wfh, Wfl, bc, bktCur);
    part_kernel<<<nPart, 256, 0, stream>>>(erow, ecol, bktCur, pairs, E, NBKT, nPart);
    csr_kernel<<<NBKT, 256, 0, stream>>>(pairs, bktCur, csr, offs, deg, dinv, N);
    gemm_kernel<<<(N + GT_M - 1) / GT_M, 256, 0, stream>>>(x, Wfh, Wfl, bc, gb, N);
    gather_kernel<<<(N + 3) / 4, 256, 0, stream>>>((const uint4*)gb, offs, deg, csr, dinv, outh, outx, N);
}

// Round 20
// 373.348 us; speedup vs baseline: 1.0696x; 1.0527x over previous
//
#include <hip/hip_runtime.h>

// Problem constants (from reference)
#define IN_CH   256
#define OUT_CH  128
#define SCALE   1.8f
#define GT_M    64      // GEMM rows per block (4 row-tiles per wave)
#define BKT_SH  8       // 256 nodes per bucket
#define BKT_CAP 9216    // fixed bucket window capacity (mean 8192 + 11 sigma)

using bf16x8 = __attribute__((ext_vector_type(8))) short;   // 8 bf16 = 4 VGPR
using f32x4  = __attribute__((ext_vector_type(4))) float;

// bf16 helpers (bit-level, round-to-nearest-even on pack)
__device__ __forceinline__ float blo(unsigned int w) { return __uint_as_float(w << 16); }
__device__ __forceinline__ float bhi(unsigned int w) { return __uint_as_float(w & 0xffff0000u); }
__device__ __forceinline__ unsigned short f2b(float f) {
    unsigned int u = __float_as_uint(f);
    u += 0x7fffu + ((u >> 16) & 1u);
    return (unsigned short)(u >> 16);
}
// split float -> hi bf16 + lo bf16 (residual)
__device__ __forceinline__ void split2(float f, unsigned short& h, unsigned short& l) {
    h = f2b(f);
    float hf = __uint_as_float((unsigned int)h << 16);
    l = f2b(f - hf);
}

// ---------------------------------------------------------------------------
// Pre-split weights into fragment-contiguous layout + init bucket cursors.
// Element W^T[ncol][kk] -> Wf[(((kk>>5)*16+(ncol>>4))*64 + ((kk>>3)&3)*16 + (ncol&15))*8 + (kk&7)]
// so each consumer fragment load is 64 lanes x consecutive 16B = 1KB coalesced.
__global__ __launch_bounds__(256) void wsplit_kernel(const float* __restrict__ W1, const float* __restrict__ b1,
                                                     const float* __restrict__ W2, const float* __restrict__ b2,
                                                     unsigned short* __restrict__ Wfh, unsigned short* __restrict__ Wfl,
                                                     float* __restrict__ bc, int* __restrict__ bktCur) {
    int n = blockIdx.x;    // 0..255 combined output column
    int k = threadIdx.x;   // 0..255 input channel
    if (n < 2) {
        int i = n * 256 + k;
        bktCur[i] = i * BKT_CAP;
    }
    float w = (n < OUT_CH) ? W2[k * OUT_CH + n] : W1[k * OUT_CH + (n - OUT_CH)];
    unsigned short h, l;
    split2(w, h, l);
    int idx = (((k >> 5) * 16 + (n >> 4)) * 64 + ((k >> 3) & 3) * 16 + (n & 15)) * 8 + (k & 7);
    Wfh[idx] = h;
    Wfl[idx] = l;
    if (k == 0) bc[n] = (n < OUT_CH) ? b2[n] : b1[n - OUT_CH];
}

// ---------------------------------------------------------------------------
// part body: partition edges into fixed-capacity bucket windows as packed 4B
// keys: key = (dstLow<<17) | src. uint4-vectorized edge streams (4/thread-iter).
__device__ __forceinline__ void part_body(char* smem, const int* __restrict__ row, const int* __restrict__ col,
                                          int* __restrict__ bktCur, unsigned int* __restrict__ pairs,
                                          int E, int NBKT, int nPart, int pb) {
    int* lh   = (int*)smem;         // [512]
    int* lcur = lh + 512;           // [512]
    int t = threadIdx.x;
    lh[t] = 0; lh[t + 256] = 0;
    __syncthreads();
    int tile = (E + nPart - 1) / nPart;
    int e0 = pb * tile;
    int e1 = min(E, e0 + tile);
    if ((tile & 3) == 0 && (e0 & 3) == 0 && e1 == e0 + tile) {
        const uint4* c4 = (const uint4*)(col + e0);
        const uint4* r4 = (const uint4*)(row + e0);
        int n4 = tile >> 2;
        for (int i = t; i < n4; i += 256) {
            uint4 c = c4[i];
            atomicAdd(&lh[c.x >> BKT_SH], 1);
            atomicAdd(&lh[c.y >> BKT_SH], 1);
            atomicAdd(&lh[c.z >> BKT_SH], 1);
            atomicAdd(&lh[c.w >> BKT_SH], 1);
        }
        __syncthreads();
        for (int b = t; b < 512; b += 256) {
            int c = (b < NBKT) ? lh[b] : 0;
            lcur[b] = (c > 0) ? atomicAdd(&bktCur[b], c) : 0;
        }
        __syncthreads();
        for (int i = t; i < n4; i += 256) {
            uint4 c = c4[i];
            uint4 r = r4[i];
            int p0 = atomicAdd(&lcur[c.x >> BKT_SH], 1); pairs[p0] = ((c.x & 255u) << 17) | r.x;
            int p1 = atomicAdd(&lcur[c.y >> BKT_SH], 1); pairs[p1] = ((c.y & 255u) << 17) | r.y;
            int p2 = atomicAdd(&lcur[c.z >> BKT_SH], 1); pairs[p2] = ((c.z & 255u) << 17) | r.z;
            int p3 = atomicAdd(&lcur[c.w >> BKT_SH], 1); pairs[p3] = ((c.w & 255u) << 17) | r.w;
        }
    } else {
        for (int i = e0 + t; i < e1; i += 256)
            atomicAdd(&lh[col[i] >> BKT_SH], 1);
        __syncthreads();
        for (int b = t; b < 512; b += 256) {
            int c = (b < NBKT) ? lh[b] : 0;
            lcur[b] = (c > 0) ? atomicAdd(&bktCur[b], c) : 0;
        }
        __syncthreads();
        for (int i = e0 + t; i < e1; i += 256) {
            int c = col[i];
            int pos = atomicAdd(&lcur[c >> BKT_SH], 1);
            pairs[pos] = ((unsigned int)(c & 255) << 17) | (unsigned int)row[i];
        }
    }
}

// ---------------------------------------------------------------------------
// csr body: per-node count + scan -> offs/deg/dinv, then scatter into the
// bucket's contiguous csr window (L2-local).
__device__ __forceinline__ void csr_body(char* smem, const unsigned int* __restrict__ pairs,
                                         const int* __restrict__ bktCur,
                                         int* __restrict__ csr, int* __restrict__ offs,
                                         int* __restrict__ deg, float* __restrict__ dinv,
                                         int N, int b) {
    int* s    = (int*)smem;           // [256]
    int* nc   = (int*)(smem + 1024);  // [256]
    int* ncur = (int*)(smem + 2048);  // [256]
    int t = threadIdx.x;
    int base = b * BKT_CAP;
    int cnt = bktCur[b] - base;

    nc[t] = 0;
    __syncthreads();
    for (int i = t; i < cnt; i += 256)
        atomicAdd(&nc[pairs[base + i] >> 17], 1);
    __syncthreads();
    int dv = nc[t];
    s[t] = dv;
    __syncthreads();
    for (int o = 1; o < 256; o <<= 1) {
        int u = (t >= o) ? s[t - o] : 0;
        __syncthreads();
        s[t] += u;
        __syncthreads();
    }
    int rel = s[t] - dv;  // exclusive
    int n = (b << BKT_SH) + t;
    if (n < N) {
        offs[n] = base + rel;
        deg[n] = dv;
        dinv[n] = 1.0f / sqrtf((float)dv + 1.0f);
    }
    ncur[t] = rel;
    __syncthreads();
    for (int i = t; i < cnt; i += 256) {
        unsigned int k = pairs[base + i];
        int node = k >> 17;
        int pos = atomicAdd(&ncur[node], 1);
        csr[base + pos] = (int)(k & 0x1FFFF);
    }
}

// ---------------------------------------------------------------------------
// gemm body: MFMA bf16 GEMM, 64 rows/block, 4 waves (64-col strip each, 4
// row-tiles x 4 col-tiles). W fragments are coalesced 1KB loads (see wsplit);
// each fragment reused across 4 row-tiles. + bias + rownorm(h) + bf16 pack.
// gb[n][0..127] = bf16(1.8/||h_n|| * h[n][c]), gb[n][128..255] = bf16(y[n][c]).
#define XPAD 264  // 256 + 8 bf16 pad
#define GEMM_SMEM (GT_M * XPAD * 2 + 2 * GT_M * 4)   // 34304B
__device__ __forceinline__ void gemm_body(char* smem, const float* __restrict__ x,
                                          const unsigned short* __restrict__ Wfh,
                                          const unsigned short* __restrict__ Wfl,
                                          const float* __restrict__ bc,
                                          unsigned short* __restrict__ gb, int blockRow, int N) {
    unsigned short* xh = (unsigned short*)smem;             // [GT_M*XPAD]
    float* sn = (float*)(smem + GT_M * XPAD * sizeof(unsigned short));  // [2*GT_M]

    int t = threadIdx.x;
    size_t row0 = (size_t)blockRow * GT_M;

    const float4* xg = (const float4*)(x + row0 * IN_CH);
#pragma unroll
    for (int i = 0; i < 16; i++) {
        int f4 = t + i * 256;        // 0..4095
        int row = f4 >> 6;
        int c4 = (f4 & 63) * 4;
        uint2 hw = {0u, 0u};
        if (row0 + row < (size_t)N) {
            float4 v = xg[f4];
            hw.x = (unsigned int)f2b(v.x) | ((unsigned int)f2b(v.y) << 16);
            hw.y = (unsigned int)f2b(v.z) | ((unsigned int)f2b(v.w) << 16);
        }
        *(uint2*)&xh[row * XPAD + c4] = hw;
    }
    __syncthreads();

    int lane = t & 63;
    int wv = t >> 6;
    int lr = lane & 15;
    int lk = (lane >> 4) * 8;

    f32x4 acc[4][4];
#pragma unroll
    for (int rt = 0; rt < 4; rt++)
#pragma unroll
        for (int ct = 0; ct < 4; ct++) acc[rt][ct] = (f32x4){0.f, 0.f, 0.f, 0.f};

#pragma unroll
    for (int kt = 0; kt < 8; kt++) {
        int k0 = kt * 32;
        bf16x8 bh[4], bl[4];
#pragma unroll
        for (int ct = 0; ct < 4; ct++) {
            int fidx = ((kt * 16 + wv * 4 + ct) * 64 + lane) * 8;
            bh[ct] = *(const bf16x8*)&Wfh[fidx];
            bl[ct] = *(const bf16x8*)&Wfl[fidx];
        }
        bf16x8 ah[4];
#pragma unroll
        for (int rt = 0; rt < 4; rt++) {
            int idx = (rt * 16 + lr) * XPAD + k0 + lk;
            ah[rt] = *(const bf16x8*)&xh[idx];
        }
#pragma unroll
        for (int rt = 0; rt < 4; rt++)
#pragma unroll
            for (int ct = 0; ct < 4; ct++) {
                acc[rt][ct] = __builtin_amdgcn_mfma_f32_16x16x32_bf16(ah[rt], bh[ct], acc[rt][ct], 0, 0, 0);
                acc[rt][ct] = __builtin_amdgcn_mfma_f32_16x16x32_bf16(ah[rt], bl[ct], acc[rt][ct], 0, 0, 0);
            }
    }
    __syncthreads();

    float bcv[4];
#pragma unroll
    for (int ct = 0; ct < 4; ct++) bcv[ct] = bc[wv * 64 + ct * 16 + lr];
#pragma unroll
    for (int rt = 0; rt < 4; rt++)
#pragma unroll
        for (int ct = 0; ct < 4; ct++)
#pragma unroll
            for (int j = 0; j < 4; j++) acc[rt][ct][j] += bcv[ct];

    if (wv < 2) {
        float nr[4][4];
#pragma unroll
        for (int rt = 0; rt < 4; rt++)
#pragma unroll
            for (int j = 0; j < 4; j++) {
                float sum = 0.f;
#pragma unroll
                for (int ct = 0; ct < 4; ct++) sum += acc[rt][ct][j] * acc[rt][ct][j];
                nr[rt][j] = sum;
            }
#pragma unroll
        for (int o = 1; o < 16; o <<= 1)
#pragma unroll
            for (int rt = 0; rt < 4; rt++)
#pragma unroll
                for (int j = 0; j < 4; j++) nr[rt][j] += __shfl_xor(nr[rt][j], o);
        if (lr == 0) {
#pragma unroll
            for (int rt = 0; rt < 4; rt++)
#pragma unroll
                for (int j = 0; j < 4; j++)
                    sn[wv * GT_M + rt * 16 + (lane >> 4) * 4 + j] = nr[rt][j];
        }
    }
    __syncthreads();

#pragma unroll
    for (int rt = 0; rt < 4; rt++) {
#pragma unroll
        for (int j = 0; j < 4; j++) {
            int rl = rt * 16 + (lane >> 4) * 4 + j;
            if (row0 + rl >= (size_t)N) continue;
            float sf;
            if (wv < 2) {
                float n2 = sn[rl] + sn[GT_M + rl];
                sf = SCALE / fmaxf(sqrtf(n2), 1e-12f);
            } else {
                sf = 1.0f;
            }
            size_t base = (row0 + rl) * 256;
#pragma unroll
            for (int ct = 0; ct < 4; ct++) {
                int col = wv * 64 + ct * 16 + lr;
                gb[base + col] = f2b(acc[rt][ct][j] * sf);
            }
        }
    }
}

// ---------------------------------------------------------------------------
// K1: part INTERLEAVED with gemm rows A (proportional block-ID mapping so
// every CU holds a mix; latency-bound part hides under gemm compute).
__global__ __launch_bounds__(256) void k1_part_gemm(const int* __restrict__ row, const int* __restrict__ col,
                                                    int* __restrict__ bktCur, unsigned int* __restrict__ pairs,
                                                    int E, int NBKT, int nPart, int total,
                                                    const float* __restrict__ x,
                                                    const unsigned short* __restrict__ Wfh,
                                                    const unsigned short* __restrict__ Wfl,
                                                    const float* __restrict__ bc,
                                                    unsigned short* __restrict__ gb, int N) {
    __shared__ __align__(16) char smem[GEMM_SMEM];
    int b = (int)blockIdx.x;
    int before = (int)(((long long)b * nPart) / total);
    int after  = (int)(((long long)(b + 1) * nPart) / total);
    if (after > before) part_body(smem, row, col, bktCur, pairs, E, NBKT, nPart, before);
    else gemm_body(smem, x, Wfh, Wfl, bc, gb, b - before, N);
}

// K2: csr INTERLEAVED with gemm rows B.
__global__ __launch_bounds__(256) void k2_csr_gemm(const unsigned int* __restrict__ pairs,
                                                   const int* __restrict__ bktCur,
                                                   int* __restrict__ csr, int* __restrict__ offs,
                                                   int* __restrict__ deg, float* __restrict__ dinv,
                                                   int N, int nCsr, int total, int gemmRowBase,
                                                   const float* __restrict__ x,
                                                   const unsigned short* __restrict__ Wfh,
                                                   const unsigned short* __restrict__ Wfl,
                                                   const float* __restrict__ bc,
                                                   unsigned short* __restrict__ gb) {
    __shared__ __align__(16) char smem[GEMM_SMEM];
    int b = (int)blockIdx.x;
    int before = (int)(((long long)b * nCsr) / total);
    int after  = (int)(((long long)(b + 1) * nCsr) / total);
    if (after > before) csr_body(smem, pairs, bktCur, csr, offs, deg, dinv, N, before);
    else gemm_body(smem, x, Wfh, Wfl, bc, gb, gemmRowBase + (b - before), N);
}

// ---------------------------------------------------------------------------
// Fused gather-propagate, both branches. One node per 64-lane wave; two
// 32-lane halves walk alternating edges of the same list; lane owns 16B
// chunk (l&31) of the 512B gb row. Per-edge dinv[src] weighting (broadcast
// load, 400KB L2-resident). Halves combine via shfl_xor(32).
// out[n] = dinv[n] * sum_{s in n + nbrs} dinv[s] * f[s]
__global__ __launch_bounds__(256) void gather_kernel(const uint4* __restrict__ gp,
                                                     const int* __restrict__ offs, const int* __restrict__ deg,
                                                     const int* __restrict__ csr, const float* __restrict__ dinv,
                                                     float* __restrict__ outh, float* __restrict__ outx, int N) {
    int t = threadIdx.x;
    int n = (blockIdx.x << 2) + (t >> 6);   // 4 waves per block, 1 node per wave
    if (n >= N) return;
    int l = t & 63;
    int half = l >> 5;   // which edge-subsequence this half-wave walks
    int cl = l & 31;     // 16B chunk index within the row

    float a0 = 0.f, a1 = 0.f, a2 = 0.f, a3 = 0.f, a4 = 0.f, a5 = 0.f, a6 = 0.f, a7 = 0.f;
    auto accumw = [&](uint4 w, float ds) {
        a0 += blo(w.x) * ds; a1 += bhi(w.x) * ds;
        a2 += blo(w.y) * ds; a3 += bhi(w.y) * ds;
        a4 += blo(w.z) * ds; a5 += bhi(w.z) * ds;
        a6 += blo(w.w) * ds; a7 += bhi(w.w) * ds;
    };

    float dn = dinv[n];
    // self loop (half 0 only; combined later)
    if (half == 0) accumw(gp[(size_t)n * 32 + cl], dn);

    int s0 = offs[n];
    int e1 = s0 + deg[n];
    int e = s0 + half;
    for (; e + 2 < e1; e += 4) {
        int sa = csr[e];
        int sb = csr[e + 2];
        float da = dinv[sa];
        float db = dinv[sb];
        uint4 wa = gp[(size_t)sa * 32 + cl];
        uint4 wb = gp[(size_t)sb * 32 + cl];
        accumw(wa, da); accumw(wb, db);
    }
    for (; e < e1; e += 2) {
        int sa = csr[e];
        accumw(gp[(size_t)sa * 32 + cl], dinv[sa]);
    }

    // combine the two halves (channels match: lane l <-> l^32)
    a0 += __shfl_xor(a0, 32);
    a1 += __shfl_xor(a1, 32);
    a2 += __shfl_xor(a2, 32);
    a3 += __shfl_xor(a3, 32);
    a4 += __shfl_xor(a4, 32);
    a5 += __shfl_xor(a5, 32);
    a6 += __shfl_xor(a6, 32);
    a7 += __shfl_xor(a7, 32);

    if (half == 0) {
        float4 v0 = {a0 * dn, a1 * dn, a2 * dn, a3 * dn};
        float4 v1 = {a4 * dn, a5 * dn, a6 * dn, a7 * dn};
        if (cl < 16) {
            float* o = &outh[(size_t)n * OUT_CH + cl * 8];
            *(float4*)o = v0;
            *(float4*)(o + 4) = v1;
        } else {
            float* o = &outx[(size_t)n * OUT_CH + (cl - 16) * 8];
            *(float4*)o = v0;
            *(float4*)(o + 4) = v1;
        }
    }
}

// ---------------------------------------------------------------------------
extern "C" void kernel_launch(void* const* d_in, const int* in_sizes, int n_in,
                              void* d_out, int out_size, void* d_ws, size_t ws_size,
                              hipStream_t stream) {
    const float* x   = (const float*)d_in[0];
    const int*   ei  = (const int*)d_in[1];   // int32 (JAX x64-disabled)
    const float* W1  = (const float*)d_in[2];
    const float* b1  = (const float*)d_in[3];
    const float* W2  = (const float*)d_in[4];
    const float* b2  = (const float*)d_in[5];

    const int N = in_sizes[0] / IN_CH;   // 100000
    const int E = in_sizes[1] / 2;       // 3200000
    const int NBKT = (N + 255) >> BKT_SH;  // 391

    float* outh = (float*)d_out;                      // branch 2 result (h) first
    float* outx = outh + (size_t)N * OUT_CH;          // branch 1 result (x_)

    // Workspace layout (pairs and gb both live concurrently)
    char* p = (char*)d_ws;
    auto take = [&](size_t bytes) {
        char* q = p;
        p += (bytes + 255) & ~(size_t)255;
        return q;
    };
    int*   deg     = (int*)take((size_t)N * sizeof(int));
    float* dinv    = (float*)take((size_t)N * sizeof(float));
    int*   offs    = (int*)take((size_t)N * sizeof(int));
    int*   bktCur  = (int*)take(512 * sizeof(int));
    float* bc      = (float*)take(256 * sizeof(float));
    unsigned short* Wfh = (unsigned short*)take(256 * 256 * sizeof(unsigned short));
    unsigned short* Wfl = (unsigned short*)take(256 * 256 * sizeof(unsigned short));
    int*   csr     = (int*)take((size_t)NBKT * BKT_CAP * sizeof(int));
    unsigned int* pairs = (unsigned int*)take((size_t)NBKT * BKT_CAP * sizeof(unsigned int));
    unsigned short* gb = (unsigned short*)take((size_t)N * 256 * sizeof(unsigned short));

    const int* erow = ei;
    const int* ecol = ei + E;

    const int nPart = 500;                          // tile = 6400 (uint4-aligned)
    const int gemmBlocks = (N + GT_M - 1) / GT_M;   // 1563
    const int gemmA = (gemmBlocks + 1) / 2;         // 782  (K1)
    const int gemmB = gemmBlocks - gemmA;           // 781  (K2)
    const int totK1 = nPart + gemmA;                // 1282
    const int totK2 = NBKT + gemmB;                 // 1172

    wsplit_kernel<<<256, 256, 0, stream>>>(W1, b1, W2, b2, Wfh, Wfl, bc, bktCur);
    k1_part_gemm<<<totK1, 256, 0, stream>>>(erow, ecol, bktCur, pairs, E, NBKT, nPart, totK1,
                                            x, Wfh, Wfl, bc, gb, N);
    k2_csr_gemm<<<totK2, 256, 0, stream>>>(pairs, bktCur, csr, offs, deg, dinv, N, NBKT, totK2, gemmA,
                                           x, Wfh, Wfl, bc, gb);
    gather_kernel<<<(N + 3) / 4, 256, 0, stream>>>((const uint4*)gb, offs, deg, csr, dinv, outh, outx, N);
}